// Round 4
// baseline (30091.980 us; speedup 1.0000x reference)
//
#include <hip/hip_runtime.h>
#include <stdint.h>

// GRU acoustic model, fp32 I/O. R4: whole recurrence on ONE CU per batch-group.
// R3 post-mortem: cross-WG exchange via L3-coherent atomics costs ~8400
// cyc/step (every wave re-reads the 20KB h tile from L3; poll retries are
// full L3 round trips with 1 wave/CU). R4: 4 WGs x 1024 threads (16 waves).
// Each WG owns 16 batch rows; all 19 hidden slices' weight B-frags live in
// that CU's registers (waves 0-2 carry 2 slices, 3-15 one). h double-buffered
// in LDS; ONE __syncthreads per step. x folded into K (LDS cols 304..316) so
// r/z gates are a single fused GEMM; n-gate keeps split h/x accumulators.
// Decoder: separate stream-ordered kernel (implicit dispatch-boundary cache
// flush makes emb visible), 1 wave per batch, fp32 shuffle GRU.
#define FEAT 13
#define EMB 300
#define BATCH 64
#define TSTEPS 2048
#define LPAD 336             // LDS row stride (bf16): 672B, 16B-aligned
#define XCOL 304             // x lives at cols 304..316; 300-303,317-335 zero
#define NSLICE 19

typedef float  floatx4 __attribute__((ext_vector_type(4)));
typedef short  shortx8 __attribute__((ext_vector_type(8)));

__device__ __forceinline__ uint16_t f2b(float f) {
  union { float f; uint32_t i; } c; c.f = f;
  uint32_t r = c.i + 0x7fffu + ((c.i >> 16) & 1u);
  return (uint16_t)(r >> 16);
}
__device__ __forceinline__ float sigf(float x) {
  return __builtin_amdgcn_rcpf(1.f + __expf(-x));
}
__device__ __forceinline__ float tanhf_(float x) {
  return 1.f - 2.f * __builtin_amdgcn_rcpf(1.f + __expf(2.f * x));
}

// B-frag for gate-row `row`: k<300 -> Whh[row][k]; 304<=k<317 -> Wih[row][k-304]
// (folded x part, suppressed for the n-gate's h-only frags); else 0.
__device__ __forceinline__ shortx8 bfrag_h(const float* __restrict__ Whh,
                                           const float* __restrict__ Wih,
                                           int row, int kt, int q, bool foldx) {
  union { uint16_t u[8]; shortx8 v; } c;
  int k0 = kt * 32 + q * 8;
#pragma unroll
  for (int e = 0; e < 8; ++e) {
    int k = k0 + e;
    float val = 0.f;
    if (k < EMB) val = Whh[row * EMB + k];
    else if (foldx && k >= XCOL && k < XCOL + FEAT) val = Wih[row * FEAT + (k - XCOL)];
    c.u[e] = f2b(val);
  }
  return c.v;
}
__device__ __forceinline__ shortx8 bfrag_x(const float* __restrict__ Wih,
                                           int row, int q) {
  union { uint16_t u[8]; shortx8 v; } c;
#pragma unroll
  for (int e = 0; e < 8; ++e) {
    int k = q * 8 + e;
    c.u[e] = f2b(k < FEAT ? Wih[row * FEAT + k] : 0.f);
  }
  return c.v;
}
__device__ __forceinline__ shortx8 bfrag_fc(const float* __restrict__ W,
                                            int row, int kt, int q) {
  union { uint16_t u[8]; shortx8 v; } c;
  int k0 = kt * 32 + q * 8;
#pragma unroll
  for (int e = 0; e < 8; ++e) {
    int k = k0 + e;
    c.u[e] = f2b(k < EMB ? W[row * EMB + k] : 0.f);
  }
  return c.v;
}

#define MFMA16(A, B, C) __builtin_amdgcn_mfma_f32_16x16x32_bf16(A, B, C, 0, 0, 0)

__launch_bounds__(1024, 1)
__global__ void gru_enc(const float* __restrict__ x,     // [64][2048][13]
                        const float* __restrict__ eWih,  // [900][13]
                        const float* __restrict__ eWhh,  // [900][300]
                        const float* __restrict__ ebih,  // [900]
                        const float* __restrict__ ebhh,  // [900]
                        const float* __restrict__ fcW,   // [300][300]
                        const float* __restrict__ fcb,   // [300]
                        float* __restrict__ out) {
  __shared__ uint16_t hlds[2 * 16 * LPAD];  // [parity][row 16][LPAD] bf16

  const int tid  = threadIdx.x;
  const int lane = tid & 63;
  const int w    = tid >> 6;        // wave 0..15
  const int nl   = lane & 15;       // MFMA row(A) / col(B,D)
  const int q    = lane >> 4;       // k-quad / D-row-quad
  const int g    = blockIdx.x;      // batch group (16 rows)

  const bool has2 = (w < 3);        // waves 0-2 carry slices 16..18 too
  const int  j0   = 16 * w + nl;                    // always < 256 < 300
  const int  j1r  = 16 * (16 + w) + nl;             // 256..303 (may exceed 299)
  const bool j1v  = has2 && (j1r < EMB);
  const int  j1   = j1v ? j1r : 0;                  // clamped for loads

  // ---- one-time: B-fragments fp32->bf16 into registers ----
  shortx8 Br0[10], Bz0[10], Bn0[10], Bx0;
  shortx8 Br1[10], Bz1[10], Bn1[10], Bx1;
#pragma unroll
  for (int kt = 0; kt < 10; ++kt) {
    Br0[kt] = bfrag_h(eWhh, eWih, 0 * EMB + j0, kt, q, true);
    Bz0[kt] = bfrag_h(eWhh, eWih, 1 * EMB + j0, kt, q, true);
    Bn0[kt] = bfrag_h(eWhh, eWih, 2 * EMB + j0, kt, q, false);
  }
  Bx0 = bfrag_x(eWih, 2 * EMB + j0, q);
  if (has2) {
#pragma unroll
    for (int kt = 0; kt < 10; ++kt) {
      Br1[kt] = bfrag_h(eWhh, eWih, 0 * EMB + j1, kt, q, true);
      Bz1[kt] = bfrag_h(eWhh, eWih, 1 * EMB + j1, kt, q, true);
      Bn1[kt] = bfrag_h(eWhh, eWih, 2 * EMB + j1, kt, q, false);
    }
    Bx1 = bfrag_x(eWih, 2 * EMB + j1, q);
  }

  const float br0 = ebih[j0] + ebhh[j0];
  const float bz0 = ebih[EMB + j0] + ebhh[EMB + j0];
  const float bin0 = ebih[2 * EMB + j0], bhn0 = ebhh[2 * EMB + j0];
  float br1 = 0.f, bz1 = 0.f, bin1 = 0.f, bhn1 = 0.f;
  if (has2) {
    br1 = ebih[j1] + ebhh[j1];
    bz1 = ebih[EMB + j1] + ebhh[EMB + j1];
    bin1 = ebih[2 * EMB + j1]; bhn1 = ebhh[2 * EMB + j1];
  }

  // ---- init LDS: zero both buffers, then x_0 into buf0 ----
  for (int i = tid; i < 2 * 16 * LPAD; i += 1024) hlds[i] = 0;
  __syncthreads();
  if (tid < 16 * FEAT) {
    int m = tid / FEAT, f = tid - m * FEAT;
    hlds[m * LPAD + XCOL + f] = f2b(x[((size_t)(g * 16 + m) * TSTEPS) * FEAT + f]);
  }

  float h0[4] = {0.f, 0.f, 0.f, 0.f};
  float h1[4] = {0.f, 0.f, 0.f, 0.f};

  // ================= encoder recurrence: 1 barrier/step =================
  for (int t = 0; t < TSTEPS; ++t) {
    __syncthreads();
    const int p = t & 1, pn = p ^ 1;

    // A fragments from LDS (shared by both slices of this wave)
    const uint16_t* arow = hlds + p * (16 * LPAD) + nl * LPAD;
    shortx8 A[10];
#pragma unroll
    for (int kt = 0; kt < 10; ++kt)
      A[kt] = *(const shortx8*)(arow + kt * 32 + q * 8);
    shortx8 Ax = *(const shortx8*)(arow + XCOL + q * 8);

    // stage x_{t+1} into the buffer we will write (independent; hides latency)
    if (t + 1 < TSTEPS && tid < 16 * FEAT) {
      int m = tid / FEAT, f = tid - m * FEAT;
      hlds[pn * (16 * LPAD) + m * LPAD + XCOL + f] =
          f2b(x[((size_t)(g * 16 + m) * TSTEPS + (t + 1)) * FEAT + f]);
    }

    floatx4 ar0 = {0.f,0.f,0.f,0.f}, az0 = {0.f,0.f,0.f,0.f};
    floatx4 anh0 = {0.f,0.f,0.f,0.f}, anx0 = {0.f,0.f,0.f,0.f};
#pragma unroll
    for (int kt = 0; kt < 10; ++kt) {
      ar0  = MFMA16(A[kt], Br0[kt], ar0);
      az0  = MFMA16(A[kt], Bz0[kt], az0);
      anh0 = MFMA16(A[kt], Bn0[kt], anh0);
    }
    anx0 = MFMA16(Ax, Bx0, anx0);

    floatx4 ar1 = {0.f,0.f,0.f,0.f}, az1 = {0.f,0.f,0.f,0.f};
    floatx4 anh1 = {0.f,0.f,0.f,0.f}, anx1 = {0.f,0.f,0.f,0.f};
    if (has2) {
#pragma unroll
      for (int kt = 0; kt < 10; ++kt) {
        ar1  = MFMA16(A[kt], Br1[kt], ar1);
        az1  = MFMA16(A[kt], Bz1[kt], az1);
        anh1 = MFMA16(A[kt], Bn1[kt], anh1);
      }
      anx1 = MFMA16(Ax, Bx1, anx1);
    }

    // gates (fp32, own h carried in regs) -> bf16 h into LDS buf pn
    uint16_t* wbuf = hlds + pn * (16 * LPAD);
#pragma unroll
    for (int i = 0; i < 4; ++i) {
      float r = sigf(ar0[i] + br0);
      float z = sigf(az0[i] + bz0);
      float n = tanhf_(anx0[i] + bin0 + r * (anh0[i] + bhn0));
      float h = z * (h0[i] - n) + n;
      h0[i] = h;
      wbuf[(q * 4 + i) * LPAD + j0] = f2b(h);
    }
    if (has2) {
#pragma unroll
      for (int i = 0; i < 4; ++i) {
        float r = sigf(ar1[i] + br1);
        float z = sigf(az1[i] + bz1);
        float n = tanhf_(anx1[i] + bin1 + r * (anh1[i] + bhn1));
        float h = z * (h1[i] - n) + n;
        h1[i] = h;
        if (j1v) wbuf[(q * 4 + i) * LPAD + j1] = f2b(h);
      }
    }
  }

  // ================= fc: emb = relu(h_T @ fcW^T + fcb) =================
  __syncthreads();  // h_T is in buffer 0 (TSTEPS even)
  {
    const uint16_t* arow = hlds + nl * LPAD;
    shortx8 A[10];
#pragma unroll
    for (int kt = 0; kt < 10; ++kt)
      A[kt] = *(const shortx8*)(arow + kt * 32 + q * 8);

    float* oemb = out + (size_t)BATCH * TSTEPS * FEAT;
    floatx4 a0 = {0.f,0.f,0.f,0.f};
#pragma unroll
    for (int kt = 0; kt < 10; ++kt)
      a0 = MFMA16(A[kt], bfrag_fc(fcW, j0, kt, q), a0);
    const float fb0 = fcb[j0];
#pragma unroll
    for (int i = 0; i < 4; ++i) {
      float e = a0[i] + fb0;
      oemb[(size_t)(g * 16 + q * 4 + i) * EMB + j0] = e > 0.f ? e : 0.f;
    }
    if (j1v) {
      floatx4 a1 = {0.f,0.f,0.f,0.f};
#pragma unroll
      for (int kt = 0; kt < 10; ++kt)
        a1 = MFMA16(A[kt], bfrag_fc(fcW, j1, kt, q), a1);
      const float fb1 = fcb[j1];
#pragma unroll
      for (int i = 0; i < 4; ++i) {
        float e = a1[i] + fb1;
        oemb[(size_t)(g * 16 + q * 4 + i) * EMB + j1] = e > 0.f ? e : 0.f;
      }
    }
  }
}

// ---------------- decoder: 1 wave per batch, all fp32 ----------------
__launch_bounds__(64, 1)
__global__ void gru_dec(const float* __restrict__ dWih,  // [39][300]
                        const float* __restrict__ dWhh,  // [39][13]
                        const float* __restrict__ dbih,  // [39]
                        const float* __restrict__ dbhh,  // [39]
                        float* __restrict__ out) {
  const int b  = blockIdx.x;
  const int lj = threadIdx.x;            // [0,13)=r [13,26)=z [26,39)=n
  const float* emb = out + (size_t)BATCH * TSTEPS * FEAT + (size_t)b * EMB;

  float Wd[FEAT];
#pragma unroll
  for (int k = 0; k < FEAT; ++k) Wd[k] = 0.f;
  float bhhv = 0.f, dgi = 0.f;
  if (lj < 3 * FEAT) {
#pragma unroll
    for (int k = 0; k < FEAT; ++k) Wd[k] = dWhh[lj * FEAT + k];
    bhhv = dbhh[lj];
    dgi  = dbih[lj];
#pragma unroll 4
    for (int k = 0; k < EMB; ++k)
      dgi = fmaf(emb[k], dWih[lj * EMB + k], dgi);
  }

  float hrep[FEAT];
#pragma unroll
  for (int k = 0; k < FEAT; ++k) hrep[k] = 0.f;
  float hown = 0.f;
  const bool nlane = (lj >= 2 * FEAT && lj < 3 * FEAT);
  float* orow = out + (size_t)b * TSTEPS * FEAT;

  for (int t = 0; t < TSTEPS; ++t) {
    float gh = bhhv;
#pragma unroll
    for (int k = 0; k < FEAT; ++k) gh = fmaf(Wd[k], hrep[k], gh);
    float sg = sigf(dgi + gh);
    float rr = __shfl(sg, (lj - 2 * FEAT) & 63);
    float zz = __shfl(sg, (lj - FEAT) & 63);
    float nn = tanhf_(dgi + rr * gh);
    float hn = zz * (hown - nn) + nn;
    bool same = (!nlane) || (hn == hown);
    if (nlane) {
      orow[t * FEAT + (lj - 2 * FEAT)] = hn;
      hown = hn;
    }
#pragma unroll
    for (int k = 0; k < FEAT; ++k) hrep[k] = __shfl(hown, 2 * FEAT + k);
    if (__all(same)) {  // exact fp32 fixed point -> rest is constant
      if (nlane) {
        for (int t2 = t + 1; t2 < TSTEPS; ++t2)
          orow[t2 * FEAT + (lj - 2 * FEAT)] = hn;
      }
      break;
    }
  }
}

extern "C" void kernel_launch(void* const* d_in, const int* in_sizes, int n_in,
                              void* d_out, int out_size, void* d_ws, size_t ws_size,
                              hipStream_t stream) {
  (void)in_sizes; (void)n_in; (void)out_size; (void)d_ws; (void)ws_size;
  const float* x    = (const float*)d_in[0];
  const float* eWih = (const float*)d_in[1];
  const float* eWhh = (const float*)d_in[2];
  const float* ebih = (const float*)d_in[3];
  const float* ebhh = (const float*)d_in[4];
  const float* fcW  = (const float*)d_in[5];
  const float* fcb  = (const float*)d_in[6];
  const float* dWih = (const float*)d_in[7];
  const float* dWhh = (const float*)d_in[8];
  const float* dbih = (const float*)d_in[9];
  const float* dbhh = (const float*)d_in[10];

  hipLaunchKernelGGL(gru_enc, dim3(4), dim3(1024), 0, stream,
                     x, eWih, eWhh, ebih, ebhh, fcW, fcb, (float*)d_out);
  hipLaunchKernelGGL(gru_dec, dim3(BATCH), dim3(64), 0, stream,
                     dWih, dWhh, dbih, dbhh, (float*)d_out);
}

// Round 5
// 11252.777 us; speedup vs baseline: 2.6742x; 2.6742x over previous
//
#include <hip/hip_runtime.h>
#include <stdint.h>

// GRU acoustic model, fp32 I/O. R5: two-level parallel recurrence.
// R4 post-mortem: 548KB bf16 weights > 512KB RF (and > 160KB LDS) of one CU
// -> massive spill (VGPR_Count 64), 30ms. R3 post-mortem: 76 waves x 20KB
// coherent tagged reads/step serialized at the L3 coherence point (8400
// cyc/step). R5: 16 WGs = 4 groups x 4 clusters; cluster = 80 (last 60)
// hidden cols, 4 waves, 1 wave/SIMD (512 VGPR budget), slice B-frags
// register-resident. Within-CU h via LDS + 1 barrier/step; cross-CU via
// tagged u32 (tag<<16|bf16) relaxed agent atomics, straggler-only retries.
// Parity double-buffer; dependency chain bounds skew to 1 step (race-free).
// Decoder: separate kernel, 1 wave/batch, fp32 shuffle GRU.
#define FEAT 13
#define EMB 300
#define BATCH 64
#define TSTEPS 2048
#define LPAD 328             // LDS row stride (u16): 656B; bank offset 4/row
#define XCOL 304             // x folded at K cols 304..316
#define KCOLS 320            // L3 hbuf row width (u32)
#define BUFW (16 * LPAD)     // u16 per parity LDS buffer

typedef float  floatx4 __attribute__((ext_vector_type(4)));
typedef short  shortx8 __attribute__((ext_vector_type(8)));

#define WS_WORDS (2 * 4 * 16 * KCOLS)   // tagged hbuf: u32[2][4][16][320]

__device__ __forceinline__ uint16_t f2b(float f) {
  union { float f; uint32_t i; } c; c.f = f;
  uint32_t r = c.i + 0x7fffu + ((c.i >> 16) & 1u);
  return (uint16_t)(r >> 16);
}
__device__ __forceinline__ float sigf(float x) {
  return __builtin_amdgcn_rcpf(1.f + __expf(-x));
}
__device__ __forceinline__ float tanhf_(float x) {
  return 1.f - 2.f * __builtin_amdgcn_rcpf(1.f + __expf(2.f * x));
}

__global__ void gru_init(uint32_t* __restrict__ ws) {
  int stride = gridDim.x * blockDim.x;
  for (int i = blockIdx.x * blockDim.x + threadIdx.x; i < WS_WORDS; i += stride)
    ws[i] = 0;  // tag 0 == "h_0 = 0 ready"
}

// B-frag builders (one-time, fp32 global reads -> bf16 regs).
// mode 0 (r/z): k<300 -> Whh[R][k]; 304<=k<317 -> Wih[R][k-304]; else 0
// mode 1 (n,h): k<300 -> Whh[R][k]; else 0
// mode 2 (n,x): 304<=k<317 -> Wih[R][k-304]; else 0   (kt must be 9)
__device__ __forceinline__ shortx8 bfrag(const float* __restrict__ Whh,
                                         const float* __restrict__ Wih,
                                         int R, int kt, int q, int mode) {
  union { uint16_t u[8]; shortx8 v; } c;
  int k0 = kt * 32 + q * 8;
#pragma unroll
  for (int e = 0; e < 8; ++e) {
    int k = k0 + e;
    float val = 0.f;
    if (mode != 2 && k < EMB) val = Whh[R * EMB + k];
    if (mode != 1 && k >= XCOL && k < XCOL + FEAT) val = Wih[R * FEAT + (k - XCOL)];
    c.u[e] = f2b(val);
  }
  return c.v;
}
__device__ __forceinline__ shortx8 bfrag_fc(const float* __restrict__ W,
                                            int row, int kt, int q) {
  union { uint16_t u[8]; shortx8 v; } c;
  int k0 = kt * 32 + q * 8;
#pragma unroll
  for (int e = 0; e < 8; ++e) {
    int k = k0 + e;
    c.u[e] = f2b(k < EMB ? W[row * EMB + k] : 0.f);
  }
  return c.v;
}

#define MFMA16(A, B, C) __builtin_amdgcn_mfma_f32_16x16x32_bf16(A, B, C, 0, 0, 0)

// Poll+fetch one partner cluster's tagged region into LDS buf.
// NPAIRS = column-pairs per row (40 for 80-col clusters, 32 for the 64-col).
template <int NPAIRS>
__device__ __forceinline__ void fetch_region(const unsigned long long* __restrict__ src,
                                             uint16_t* __restrict__ wb, int c0, int lane,
                                             unsigned long long TT) {
  constexpr int CNT = NPAIRS / 4;   // 16*NPAIRS/64 per lane
  unsigned long long v[CNT];
  int rw[CNT], pr[CNT], sm = 0;
#pragma unroll
  for (int i = 0; i < CNT; ++i) {
    int idx = i * 64 + lane;
    rw[i] = idx / NPAIRS; pr[i] = idx - rw[i] * NPAIRS;
    v[i] = __hip_atomic_load(src + rw[i] * (KCOLS / 2) + pr[i], __ATOMIC_RELAXED,
                             __HIP_MEMORY_SCOPE_AGENT);
    if ((v[i] ^ TT) & 0xFFFF0000FFFF0000ULL) sm |= 1 << i;
  }
  while (__any(sm)) {
#pragma unroll
    for (int i = 0; i < CNT; ++i) if (sm & (1 << i)) {
      v[i] = __hip_atomic_load(src + rw[i] * (KCOLS / 2) + pr[i], __ATOMIC_RELAXED,
                               __HIP_MEMORY_SCOPE_AGENT);
      if (!((v[i] ^ TT) & 0xFFFF0000FFFF0000ULL)) sm &= ~(1 << i);
    }
  }
#pragma unroll
  for (int i = 0; i < CNT; ++i) {
    uint32_t pk = __builtin_amdgcn_perm((uint32_t)(v[i] >> 32), (uint32_t)v[i], 0x05040100u);
    *(uint32_t*)(wb + rw[i] * LPAD + c0 + 2 * pr[i]) = pk;
  }
}

__launch_bounds__(256, 1)
__global__ void gru_enc(const float* __restrict__ x,     // [64][2048][13]
                        const float* __restrict__ eWih,  // [900][13]
                        const float* __restrict__ eWhh,  // [900][300]
                        const float* __restrict__ ebih,  // [900]
                        const float* __restrict__ ebhh,  // [900]
                        const float* __restrict__ fcW,   // [300][300]
                        const float* __restrict__ fcb,   // [300]
                        float* __restrict__ out,
                        uint32_t* __restrict__ hbuf) {
  __shared__ uint16_t hlds[2 * BUFW];

  const int tid = threadIdx.x, lane = tid & 63, w = tid >> 6;
  const int nl = lane & 15, q = lane >> 4;
  const int g = blockIdx.x >> 2;      // batch group (16 rows)
  const int c = blockIdx.x & 3;       // hidden cluster

  const bool has2 = (w == c) && (c < 3);     // x-duty wave carries slice 4
  const int  j1r = 80 * c + 16 * w + nl;     // primary slice col
  const bool j1v = (j1r < EMB);
  const int  j1  = j1v ? j1r : 0;
  const int  j2  = 80 * c + 64 + nl;         // second slice col (<300 always)

  // ---- one-time: weight B-fragments into registers ----
  shortx8 Br1[10], Bz1[10], Bn1[10], Bnx1;
  shortx8 Br2[10], Bz2[10], Bn2[10], Bnx2;
#pragma unroll
  for (int kt = 0; kt < 10; ++kt) {
    Br1[kt] = bfrag(eWhh, eWih, 0 * EMB + j1, kt, q, 0);
    Bz1[kt] = bfrag(eWhh, eWih, 1 * EMB + j1, kt, q, 0);
    Bn1[kt] = bfrag(eWhh, eWih, 2 * EMB + j1, kt, q, 1);
  }
  Bnx1 = bfrag(eWhh, eWih, 2 * EMB + j1, 9, q, 2);
  if (has2) {
#pragma unroll
    for (int kt = 0; kt < 10; ++kt) {
      Br2[kt] = bfrag(eWhh, eWih, 0 * EMB + j2, kt, q, 0);
      Bz2[kt] = bfrag(eWhh, eWih, 1 * EMB + j2, kt, q, 0);
      Bn2[kt] = bfrag(eWhh, eWih, 2 * EMB + j2, kt, q, 1);
    }
    Bnx2 = bfrag(eWhh, eWih, 2 * EMB + j2, 9, q, 2);
  }
  const float br1 = ebih[j1] + ebhh[j1];
  const float bz1 = ebih[EMB + j1] + ebhh[EMB + j1];
  const float bin1 = ebih[2 * EMB + j1], bhn1 = ebhh[2 * EMB + j1];
  float br2 = 0.f, bz2 = 0.f, bin2 = 0.f, bhn2 = 0.f;
  if (has2) {
    br2 = ebih[j2] + ebhh[j2];
    bz2 = ebih[EMB + j2] + ebhh[EMB + j2];
    bin2 = ebih[2 * EMB + j2]; bhn2 = ebhh[2 * EMB + j2];
  }

  // ---- init LDS (both parities zero), stage x_0 into buf 0 ----
  for (int i = tid; i < 2 * BUFW; i += 256) hlds[i] = 0;
  __syncthreads();
  for (int i = tid; i < 16 * FEAT; i += 256) {
    int m = i / FEAT, f = i - m * FEAT;
    hlds[m * LPAD + XCOL + f] = f2b(x[((size_t)(g * 16 + m) * TSTEPS) * FEAT + f]);
  }
  __syncthreads();

  float h1c[4] = {0.f, 0.f, 0.f, 0.f};
  float h2c[4] = {0.f, 0.f, 0.f, 0.f};

  // ================= recurrence: 1 barrier/step =================
  for (int t = 1; t <= TSTEPS; ++t) {
    const int p = (t - 1) & 1, pn = p ^ 1;

    // A fragments (h_{t-1} ++ x_{t-1}) from LDS buf p
    const uint16_t* arow = hlds + p * BUFW + nl * LPAD;
    shortx8 A[10];
#pragma unroll
    for (int kt = 0; kt < 10; ++kt)
      A[kt] = *(const shortx8*)(arow + kt * 32 + q * 8);

    floatx4 ar1 = {0.f,0.f,0.f,0.f}, az1 = {0.f,0.f,0.f,0.f};
    floatx4 anh1 = {0.f,0.f,0.f,0.f}, anx1 = {0.f,0.f,0.f,0.f};
#pragma unroll
    for (int kt = 0; kt < 10; ++kt) {
      ar1  = MFMA16(A[kt], Br1[kt], ar1);
      az1  = MFMA16(A[kt], Bz1[kt], az1);
      anh1 = MFMA16(A[kt], Bn1[kt], anh1);
    }
    anx1 = MFMA16(A[9], Bnx1, anx1);
    floatx4 ar2 = {0.f,0.f,0.f,0.f}, az2 = {0.f,0.f,0.f,0.f};
    floatx4 anh2 = {0.f,0.f,0.f,0.f}, anx2 = {0.f,0.f,0.f,0.f};
    if (has2) {
#pragma unroll
      for (int kt = 0; kt < 10; ++kt) {
        ar2  = MFMA16(A[kt], Br2[kt], ar2);
        az2  = MFMA16(A[kt], Bz2[kt], az2);
        anh2 = MFMA16(A[kt], Bn2[kt], anh2);
      }
      anx2 = MFMA16(A[9], Bnx2, anx2);
    }

    // gates -> h_t: LDS buf pn + tagged L3 publish
    uint16_t* wb = hlds + pn * BUFW;
    uint32_t* gb = hbuf + (size_t)((pn * 4 + g) * 16) * KCOLS;
    const uint32_t tg = ((uint32_t)t) << 16;
#pragma unroll
    for (int i = 0; i < 4; ++i) {
      float r = sigf(ar1[i] + br1);
      float z = sigf(az1[i] + bz1);
      float n = tanhf_(anx1[i] + bin1 + r * (anh1[i] + bhn1));
      float h = z * (h1c[i] - n) + n;
      h1c[i] = h;
      if (j1v) {
        uint16_t hb = f2b(h);
        wb[(q * 4 + i) * LPAD + j1] = hb;
        __hip_atomic_store(gb + (q * 4 + i) * KCOLS + j1, tg | hb, __ATOMIC_RELAXED,
                           __HIP_MEMORY_SCOPE_AGENT);
      }
    }
    if (has2) {
#pragma unroll
      for (int i = 0; i < 4; ++i) {
        float r = sigf(ar2[i] + br2);
        float z = sigf(az2[i] + bz2);
        float n = tanhf_(anx2[i] + bin2 + r * (anh2[i] + bhn2));
        float h = z * (h2c[i] - n) + n;
        h2c[i] = h;
        uint16_t hb = f2b(h);
        wb[(q * 4 + i) * LPAD + j2] = hb;
        __hip_atomic_store(gb + (q * 4 + i) * KCOLS + j2, tg | hb, __ATOMIC_RELAXED,
                           __HIP_MEMORY_SCOPE_AGENT);
      }
    }
    if (c == 3 && w == 3) {  // tag pad cols 300..303 (readers stay uniform)
      int row = lane >> 2, col = 300 + (lane & 3);
      __hip_atomic_store(gb + row * KCOLS + col, tg, __ATOMIC_RELAXED,
                         __HIP_MEMORY_SCOPE_AGENT);
    }

    if (w == c) {
      // x-duty: stage x_t into buf pn (consumed at step t+1)
      if (t < TSTEPS) {
        for (int i = lane; i < 16 * FEAT; i += 64) {
          int m = i / FEAT, f = i - m * FEAT;
          wb[m * LPAD + XCOL + f] =
              f2b(x[((size_t)(g * 16 + m) * TSTEPS + t) * FEAT + f]);
        }
      }
    } else {
      // fetch partner cluster w's h_t (tag t) from L3 -> LDS buf pn
      const int pc = w, c0 = 80 * pc;
      const unsigned long long* src =
          (const unsigned long long*)hbuf + (size_t)((pn * 4 + g) * 16) * (KCOLS / 2) + c0 / 2;
      const unsigned long long TT =
          (((unsigned long long)t) << 16) | (((unsigned long long)t) << 48);
      if (pc < 3) fetch_region<40>(src, wb, c0, lane, TT);
      else        fetch_region<32>(src, wb, c0, lane, TT);
    }
    __syncthreads();
  }

  // ================= fc: emb = relu(h_T @ fcW^T + fcb) =================
  {
    const uint16_t* arow = hlds + nl * LPAD;   // h_T in buf 0 (TSTEPS even)
    shortx8 A[10];
#pragma unroll
    for (int kt = 0; kt < 10; ++kt)
      A[kt] = *(const shortx8*)(arow + kt * 32 + q * 8);
    float* oemb = out + (size_t)BATCH * TSTEPS * FEAT;

    floatx4 a1 = {0.f,0.f,0.f,0.f};
#pragma unroll
    for (int kt = 0; kt < 10; ++kt)
      a1 = MFMA16(A[kt], bfrag_fc(fcW, j1, kt, q), a1);
    const float fb1 = fcb[j1];
#pragma unroll
    for (int i = 0; i < 4; ++i) {
      float e = a1[i] + fb1;
      if (j1v) oemb[(size_t)(g * 16 + q * 4 + i) * EMB + j1] = e > 0.f ? e : 0.f;
    }
    if (has2) {
      floatx4 a2 = {0.f,0.f,0.f,0.f};
#pragma unroll
      for (int kt = 0; kt < 10; ++kt)
        a2 = MFMA16(A[kt], bfrag_fc(fcW, j2, kt, q), a2);
      const float fb2 = fcb[j2];
#pragma unroll
      for (int i = 0; i < 4; ++i) {
        float e = a2[i] + fb2;
        oemb[(size_t)(g * 16 + q * 4 + i) * EMB + j2] = e > 0.f ? e : 0.f;
      }
    }
  }
}

// ---------------- decoder: 1 wave per batch, all fp32 ----------------
__launch_bounds__(64, 1)
__global__ void gru_dec(const float* __restrict__ dWih,  // [39][300]
                        const float* __restrict__ dWhh,  // [39][13]
                        const float* __restrict__ dbih,  // [39]
                        const float* __restrict__ dbhh,  // [39]
                        float* __restrict__ out) {
  const int b  = blockIdx.x;
  const int lj = threadIdx.x;            // [0,13)=r [13,26)=z [26,39)=n
  const float* emb = out + (size_t)BATCH * TSTEPS * FEAT + (size_t)b * EMB;

  float Wd[FEAT];
#pragma unroll
  for (int k = 0; k < FEAT; ++k) Wd[k] = 0.f;
  float bhhv = 0.f, dgi = 0.f;
  if (lj < 3 * FEAT) {
#pragma unroll
    for (int k = 0; k < FEAT; ++k) Wd[k] = dWhh[lj * FEAT + k];
    bhhv = dbhh[lj];
    dgi  = dbih[lj];
#pragma unroll 4
    for (int k = 0; k < EMB; ++k)
      dgi = fmaf(emb[k], dWih[lj * EMB + k], dgi);
  }

  float hrep[FEAT];
#pragma unroll
  for (int k = 0; k < FEAT; ++k) hrep[k] = 0.f;
  float hown = 0.f;
  const bool nlane = (lj >= 2 * FEAT && lj < 3 * FEAT);
  float* orow = out + (size_t)b * TSTEPS * FEAT;

  for (int t = 0; t < TSTEPS; ++t) {
    float gh = bhhv;
#pragma unroll
    for (int k = 0; k < FEAT; ++k) gh = fmaf(Wd[k], hrep[k], gh);
    float sg = sigf(dgi + gh);
    float rr = __shfl(sg, (lj - 2 * FEAT) & 63);
    float zz = __shfl(sg, (lj - FEAT) & 63);
    float nn = tanhf_(dgi + rr * gh);
    float hn = zz * (hown - nn) + nn;
    bool same = (!nlane) || (hn == hown);
    if (nlane) {
      orow[t * FEAT + (lj - 2 * FEAT)] = hn;
      hown = hn;
    }
#pragma unroll
    for (int k = 0; k < FEAT; ++k) hrep[k] = __shfl(hown, 2 * FEAT + k);
    if (__all(same)) {  // exact fp32 fixed point -> rest constant
      if (nlane) {
        for (int t2 = t + 1; t2 < TSTEPS; ++t2)
          orow[t2 * FEAT + (lj - 2 * FEAT)] = hn;
      }
      break;
    }
  }
}

extern "C" void kernel_launch(void* const* d_in, const int* in_sizes, int n_in,
                              void* d_out, int out_size, void* d_ws, size_t ws_size,
                              hipStream_t stream) {
  (void)in_sizes; (void)n_in; (void)out_size; (void)ws_size;
  const float* x    = (const float*)d_in[0];
  const float* eWih = (const float*)d_in[1];
  const float* eWhh = (const float*)d_in[2];
  const float* ebih = (const float*)d_in[3];
  const float* ebhh = (const float*)d_in[4];
  const float* fcW  = (const float*)d_in[5];
  const float* fcb  = (const float*)d_in[6];
  const float* dWih = (const float*)d_in[7];
  const float* dWhh = (const float*)d_in[8];
  const float* dbih = (const float*)d_in[9];
  const float* dbhh = (const float*)d_in[10];

  hipLaunchKernelGGL(gru_init, dim3(32), dim3(256), 0, stream, (uint32_t*)d_ws);
  hipLaunchKernelGGL(gru_enc, dim3(16), dim3(256), 0, stream,
                     x, eWih, eWhh, ebih, ebhh, fcW, fcb, (float*)d_out,
                     (uint32_t*)d_ws);
  hipLaunchKernelGGL(gru_dec, dim3(BATCH), dim3(64), 0, stream,
                     dWih, dWhh, dbih, dbhh, (float*)d_out);
}